// Round 4
// baseline (367.754 us; speedup 1.0000x reference)
//
#include <hip/hip_runtime.h>

#define NODES 1430
#define GENE0 1421
#define NHEADS 9
#define GMAX 64              // max bucketed in-edges per gene (Poisson(8) tail ~0)
#define QCAP 1024            // hit-queue capacity (fallback scatter)
#define L1B 1024             // threads/block for LDS-flag scatter
#define L1QCAP 3072          // hit-queue capacity (LDS-flag kernel)
#define DEGB 1024            // threads/block for k_deg

__device__ __forceinline__ float frelu(float v) { return v > 0.f ? v : 0.f; }

// Pass 1 (new): SINGLE-PASS degree count via direct global atomics.
// Replaces the R=3 LDS nibble histogram + copies round-trip + k_reduce SWAR:
// deg cells (2.9 MB) are L2-resident; 5.86M atomicAdds ~= 23K transactions/CU
// (~10 us floor), vs the old 47 MB redundant edge re-reads + 61 MB copies
// traffic + an extra dispatch. Gene detection fused (esrc fetched only for
// the 0.63% gene edges). 8 independent int4 streams for load ILP.
__global__ __launch_bounds__(DEGB, 2)
void k_deg(const int* __restrict__ esrc, const int* __restrict__ edst,
           int* __restrict__ deg,
           int* __restrict__ gene_cnt, int* __restrict__ gene_src,
           unsigned int* __restrict__ flagw, int e) {
    const int tid = threadIdx.x;
    const int e4 = e >> 2;
    const int nb = gridDim.x;
    const int Q = (e4 + nb - 1) / nb;
    const int beg = blockIdx.x * Q;
    const int end = min(beg + Q, e4);
    const int len = (end > beg) ? (end - beg) : 0;
    const int4* ed4 = (const int4*)edst;
    const int eighth = len >> 3;

    auto proc = [&](int4 d4, int j4) {
#pragma unroll
        for (int c = 0; c < 4; c++) {
            unsigned int d = (unsigned int)((&d4.x)[c]);
            atomicAdd(&deg[d], 1);
            unsigned int graph = d / NODES;          // magic-mul div
            unsigned int pos = d - graph * NODES;
            if (pos >= GENE0) {
                int s = esrc[4 * j4 + c];            // rare random load
                atomicOr(&flagw[(unsigned)s >> 5], 1u << (s & 31));
                int g = (int)(graph * NHEADS + (pos - GENE0));
                int p = atomicAdd(gene_cnt + g, 1);
                if (p < GMAX) gene_src[(g << 6) + p] = s;
            }
        }
    };

    for (int i = tid; i < eighth; i += DEGB) {
        int j0 = beg + i;
        int4 v0 = ed4[j0];
        int4 v1 = ed4[j0 + eighth];
        int4 v2 = ed4[j0 + 2 * eighth];
        int4 v3 = ed4[j0 + 3 * eighth];
        int4 v4 = ed4[j0 + 4 * eighth];
        int4 v5 = ed4[j0 + 5 * eighth];
        int4 v6 = ed4[j0 + 6 * eighth];
        int4 v7 = ed4[j0 + 7 * eighth];
        proc(v0, j0);
        proc(v1, j0 + eighth);
        proc(v2, j0 + 2 * eighth);
        proc(v3, j0 + 3 * eighth);
        proc(v4, j0 + 4 * eighth);
        proc(v5, j0 + 5 * eighth);
        proc(v6, j0 + 6 * eighth);
        proc(v7, j0 + 7 * eighth);
    }
    for (int i = (eighth << 3) + tid; i < len; i += DEGB) {
        proc(ed4[beg + i], beg + i);
    }
    // tail edges (e % 4)
    if (blockIdx.x == 0) {
        for (int j = (e4 << 2) + tid; j < e; j += DEGB) {
            unsigned int d = (unsigned int)edst[j];
            atomicAdd(&deg[d], 1);
            unsigned int graph = d / NODES;
            unsigned int pos = d - graph * NODES;
            if (pos >= GENE0) {
                int s = esrc[j];
                atomicOr(&flagw[(unsigned)s >> 5], 1u << (s & 31));
                int g = (int)(graph * NHEADS + (pos - GENE0));
                int p = atomicAdd(gene_cnt + g, 1);
                if (p < GMAX) gene_src[(g << 6) + p] = s;
            }
        }
    }
}

// Pass 2 (new): deg -> dx = {dinv, dinv*x}, zero t, set gene-node flag bits.
// Fully coalesced, ~15 MB total, replaces the K=80 SWAR reduce.
__global__ void k_dx(const int* __restrict__ deg, const float* __restrict__ x,
                     float2* __restrict__ dx, float* __restrict__ t,
                     unsigned int* __restrict__ flagw, int n) {
    int i0 = (blockIdx.x * blockDim.x + threadIdx.x) << 3;
    if (i0 >= n) return;
    float4 z4 = {0.f, 0.f, 0.f, 0.f};
    if (i0 + 7 < n) {
        int4 d0 = *(const int4*)(deg + i0);
        int4 d1 = *(const int4*)(deg + i0 + 4);
        float4 xa = *(const float4*)(x + i0);
        float4 xb = *(const float4*)(x + i0 + 4);
        float v[8];
        v[0] = rsqrtf((float)d0.x + 1.f);
        v[1] = rsqrtf((float)d0.y + 1.f);
        v[2] = rsqrtf((float)d0.z + 1.f);
        v[3] = rsqrtf((float)d0.w + 1.f);
        v[4] = rsqrtf((float)d1.x + 1.f);
        v[5] = rsqrtf((float)d1.y + 1.f);
        v[6] = rsqrtf((float)d1.z + 1.f);
        v[7] = rsqrtf((float)d1.w + 1.f);
        float4 p0 = {v[0], v[0] * xa.x, v[1], v[1] * xa.y};
        float4 p1 = {v[2], v[2] * xa.z, v[3], v[3] * xa.w};
        float4 p2 = {v[4], v[4] * xb.x, v[5], v[5] * xb.y};
        float4 p3 = {v[6], v[6] * xb.z, v[7], v[7] * xb.w};
        float4* dst = (float4*)(dx + i0);
        dst[0] = p0; dst[1] = p1; dst[2] = p2; dst[3] = p3;
        *(float4*)(t + i0) = z4;
        *(float4*)(t + i0 + 4) = z4;
    } else {
        for (int b = 0; b < 8; b++)
            if (i0 + b < n) {
                float dv = rsqrtf((float)deg[i0 + b] + 1.f);
                dx[i0 + b] = make_float2(dv, dv * x[i0 + b]);
                t[i0 + b] = 0.f;
            }
    }
    // gene nodes also need t -> set their flag bits (same as old k_reduce)
#pragma unroll
    for (int b = 0; b < 8; b++) {
        int i = i0 + b;
        if (i < n) {
            unsigned int graph = (unsigned int)i / NODES;
            unsigned int pos = (unsigned int)i - graph * NODES;
            if (pos >= GENE0) atomicOr(&flagw[(unsigned)i >> 5], 1u << (i & 31));
        }
    }
}

// Pass 3: layer-1 scatter, LDS flag bitmap, dst-only scan; hits enqueue the
// edge index; two-phase drain (idx->src, then src->dx->atomic).
__global__ __launch_bounds__(L1B, 4)
void k_l1_scatter_lds(const int* __restrict__ esrc, const int* __restrict__ edst,
                      const float2* __restrict__ dx,
                      const unsigned int* __restrict__ flagw,
                      float* __restrict__ t, int e, int nw) {
    extern __shared__ unsigned int sh[];
    unsigned int* fl = sh;                    // nw words
    int2* q = (int2*)(sh + ((nw + 3) & ~3));
    __shared__ int qn;
    const int tid = threadIdx.x;
    if (tid == 0) qn = 0;
    {
        const uint4* g4 = (const uint4*)flagw;
        uint4* l4 = (uint4*)fl;
        int nw4 = nw >> 2;
        for (int w = tid; w < nw4; w += L1B) l4[w] = g4[w];
        for (int w = (nw4 << 2) + tid; w < nw; w += L1B) fl[w] = flagw[w];
    }
    __syncthreads();

    const int e4 = e >> 2;
    const int nb = gridDim.x;
    const int Q = (e4 + nb - 1) / nb;
    const int beg = blockIdx.x * Q;
    const int end = min(beg + Q, e4);
    const int len = (end > beg) ? (end - beg) : 0;
    const int4* ed4 = (const int4*)edst;

    auto test = [&](int4 dd, int j4) {
#pragma unroll
        for (int c = 0; c < 4; c++) {
            int d = (&dd.x)[c];
            if ((fl[(unsigned)d >> 5] >> (d & 31)) & 1u) {
                int p = atomicAdd(&qn, 1);
                if (p < L1QCAP) q[p] = make_int2(4 * j4 + c, d);
                else atomicAdd(t + d, dx[esrc[4 * j4 + c]].y);
            }
        }
    };

    const int quarter = len >> 2;
    for (int i = tid; i < quarter; i += L1B) {
        int j0 = beg + i;
        int4 d0 = ed4[j0];
        int4 d1 = ed4[j0 + quarter];
        int4 d2 = ed4[j0 + 2 * quarter];
        int4 d3 = ed4[j0 + 3 * quarter];
        test(d0, j0);
        test(d1, j0 + quarter);
        test(d2, j0 + 2 * quarter);
        test(d3, j0 + 3 * quarter);
    }
    for (int i = (quarter << 2) + tid; i < len; i += L1B) {
        test(ed4[beg + i], beg + i);
    }
    if (blockIdx.x == 0) {
        for (int j = (e4 << 2) + tid; j < e; j += L1B) {
            int d = edst[j];
            if ((fl[(unsigned)d >> 5] >> (d & 31)) & 1u)
                atomicAdd(t + d, dx[esrc[j]].y);
        }
    }
    __syncthreads();
    int m = min(qn, L1QCAP);
    for (int i = tid; i < m; i += L1B) {
        int2 jd = q[i];
        q[i].x = esrc[jd.x];
    }
    __syncthreads();
    for (int i = tid; i < m; i += L1B) {
        int2 sd = q[i];
        atomicAdd(t + sd.y, dx[sd.x].y);
    }
}

// Fallback pass 3 (proven): global flag reads, 2048 edges/block.
__global__ __launch_bounds__(256, 8)
void k_l1_scatter_g(const int* __restrict__ esrc, const int* __restrict__ edst,
                    const float2* __restrict__ dx,
                    const unsigned int* __restrict__ flagw,
                    float* __restrict__ t, int e) {
    __shared__ int2 q[QCAP];
    __shared__ int qn;
    const int tid = threadIdx.x;
    if (tid == 0) qn = 0;
    __syncthreads();

    const int4* ed4 = (const int4*)edst;
    const int4* es4 = (const int4*)esrc;
    const int e4 = e >> 2;
    const int g0 = blockIdx.x * 512;
#pragma unroll
    for (int u = 0; u < 2; u++) {
        int gi = g0 + u * 256 + tid;
        if (gi < e4) {
            int4 dd = ed4[gi];
            int4 ss = es4[gi];
#pragma unroll
            for (int c = 0; c < 4; c++) {
                int d = (&dd.x)[c];
                if ((flagw[(unsigned)d >> 5] >> (d & 31)) & 1u) {
                    int p = atomicAdd(&qn, 1);
                    if (p < QCAP) q[p] = make_int2((&ss.x)[c], d);
                    else atomicAdd(t + d, dx[(&ss.x)[c]].y);
                }
            }
        }
    }
    if (blockIdx.x == 0) {
        for (int j = (e4 << 2) + tid; j < e; j += 256) {
            int d = edst[j];
            if ((flagw[(unsigned)d >> 5] >> (d & 31)) & 1u) {
                int s = esrc[j];
                atomicAdd(t + d, dx[s].y);
            }
        }
    }
    __syncthreads();
    int m = min(qn, QCAP);
    for (int i = tid; i < m; i += 256) {
        int2 sd = q[i];
        atomicAdd(t + sd.y, dx[sd.x].y);
    }
}

// Pass 4 (channel-parallel): one WAVE per gene.
__global__ void k_gene_final(const int* __restrict__ gene_cnt, const int* __restrict__ gene_src,
                             const float* __restrict__ t, const float2* __restrict__ dx,
                             const float* __restrict__ W1, const float* __restrict__ b1,
                             const float* __restrict__ W2, const float* __restrict__ b2,
                             const float* __restrict__ fw1, const float* __restrict__ fb1,
                             const float* __restrict__ fw2, const float* __restrict__ fb2,
                             float* __restrict__ out, int NG, int G) {
    int wid = (blockIdx.x * blockDim.x + threadIdx.x) >> 6;
    int lane = threadIdx.x & 63;
    if (wid >= NG) return;
    int g = wid;
    int graph = g / NHEADS;
    int head = g - graph * NHEADS;
    int node = graph * NODES + GENE0 + head;
    const int c = lane & 15;
    const int slot = lane >> 4;

    int cnt = min(gene_cnt[g], GMAX);

    float w1r[16], b1r[16], w2c[16];
#pragma unroll
    for (int kk = 0; kk < 16; kk++) {
        w1r[kk] = W1[kk];
        b1r[kk] = b1[kk];
        w2c[kk] = W2[kk * 16 + c];
    }
    float2 dn2 = dx[node];
    float tn = t[node];

    float acc = 0.f;
    const int base = g << 6;
    for (int i = slot; i < cnt; i += 8) {
        int s0 = gene_src[base + i];
        int i1 = i + 4;
        int s1 = (i1 < cnt) ? gene_src[base + i1] : -1;
        float2 a2 = dx[s0];
        float ta = t[s0];
        float2 b2v = (s1 >= 0) ? dx[s1] : make_float2(0.f, 0.f);
        float tb = (s1 >= 0) ? t[s1] : 0.f;
        {
            float us = a2.x * ta + a2.x * a2.y;
            float m = 0.f;
#pragma unroll
            for (int kk = 0; kk < 16; kk++)
                m += frelu(us * w1r[kk] + b1r[kk]) * w2c[kk];
            acc += a2.x * m;
        }
        if (s1 >= 0) {
            float us = b2v.x * tb + b2v.x * b2v.y;
            float m = 0.f;
#pragma unroll
            for (int kk = 0; kk < 16; kk++)
                m += frelu(us * w1r[kk] + b1r[kk]) * w2c[kk];
            acc += b2v.x * m;
        }
    }
    acc += __shfl_xor(acc, 16, 64);
    acc += __shfl_xor(acc, 32, 64);

    float dn = dn2.x;
    float un = dn * tn + dn * dn2.y;
    float h2 = 0.f;
#pragma unroll
    for (int kk = 0; kk < 16; kk++)
        h2 += frelu(un * w1r[kk] + b1r[kk]) * w2c[kk];
    float h = frelu(dn * acc + dn * dn * h2 + b2[c]);

    float hv[16];
#pragma unroll
    for (int c2 = 0; c2 < 16; c2++) hv[c2] = __shfl(h, c2, 64);

    int kk = lane & 7;
    float z = fb1[head * 8 + kk];
#pragma unroll
    for (int c2 = 0; c2 < 16; c2++) z += hv[c2] * fw1[head * 128 + c2 * 8 + kk];
    float term = frelu(z) * fw2[head * 8 + kk];
    term += __shfl_xor(term, 1, 64);
    term += __shfl_xor(term, 2, 64);
    term += __shfl_xor(term, 4, 64);
    if (lane == 0) out[head * G + graph] = fb2[head] + term;
}

extern "C" void kernel_launch(void* const* d_in, const int* in_sizes, int n_in,
                              void* d_out, int out_size, void* d_ws, size_t ws_size,
                              hipStream_t stream) {
    const float* x   = (const float*)d_in[0];
    const int*   ei  = (const int*)d_in[1];
    const float* W1  = (const float*)d_in[3];
    const float* b1  = (const float*)d_in[4];
    const float* W2  = (const float*)d_in[5];
    const float* b2  = (const float*)d_in[6];
    const float* fw1 = (const float*)d_in[7];
    const float* fb1 = (const float*)d_in[8];
    const float* fw2 = (const float*)d_in[9];
    const float* fb2 = (const float*)d_in[10];

    int n = in_sizes[0];
    int e = in_sizes[1] / 2;
    int G = in_sizes[2] / NHEADS;
    int NG = G * NHEADS;
    const int* esrc = ei;
    const int* edst = ei + e;

    int nw = (n + 31) / 32;                                   // flag words
    size_t l1_shmem = (size_t)((nw + 3) & ~3) * 4 + (size_t)L1QCAP * 8;

    // One-time dyn-LDS attribute setup for the scatter (gfx950: 160 KiB/CU).
    static int L1_LDS_OK = 0;
    if (L1_LDS_OK == 0) {
        hipError_t st2 = hipFuncSetAttribute(
            reinterpret_cast<const void*>(k_l1_scatter_lds),
            hipFuncAttributeMaxDynamicSharedMemorySize, (int)l1_shmem);
        L1_LDS_OK = (st2 == hipSuccess && l1_shmem <= 160 * 1024) ? 1 : -1;
    }

    char* ws = (char*)d_ws;
    size_t off = 0;
    auto alloc = [&](size_t bytes) {
        char* p = ws + off;
        off += (bytes + 255) & ~(size_t)255;
        return p;
    };
    int*   gene_cnt      = (int*)alloc((size_t)NG * 4);
    unsigned int* flagw  = (unsigned int*)alloc((size_t)nw * 4);
    int*   deg           = (int*)alloc((size_t)n * 4);        // zeroed below
    size_t zero_bytes    = off;                               // ~3 MB
    int*    gene_src     = (int*)alloc((size_t)NG * GMAX * 4);
    float*  t            = (float*)alloc((size_t)n * 4);      // zeroed by k_dx
    float2* dx           = (float2*)alloc((size_t)n * 8);     // {dinv, dinv*x}
    (void)n_in; (void)out_size; (void)ws_size;

    hipMemsetAsync(d_ws, 0, zero_bytes, stream);

    const int B = 256;
    k_deg<<<512, DEGB, 0, stream>>>(esrc, edst, deg, gene_cnt, gene_src, flagw, e);
    int nthr = (n + 7) >> 3;
    k_dx<<<(nthr + B - 1) / B, B, 0, stream>>>(deg, x, dx, t, flagw, n);
    if (L1_LDS_OK == 1) {
        k_l1_scatter_lds<<<256, L1B, l1_shmem, stream>>>(esrc, edst, dx, flagw, t, e, nw);
    } else {
        int nblk = ((e >> 2) + 511) / 512;
        k_l1_scatter_g<<<nblk, 256, 0, stream>>>(esrc, edst, dx, flagw, t, e);
    }
    int waves_blocks = (NG * 64 + B - 1) / B;
    k_gene_final<<<waves_blocks, B, 0, stream>>>(gene_cnt, gene_src, t, dx,
                                                 W1, b1, W2, b2,
                                                 fw1, fb1, fw2, fb2,
                                                 (float*)d_out, NG, G);
}

// Round 5
// 355.791 us; speedup vs baseline: 1.0336x; 1.0336x over previous
//
#include <hip/hip_runtime.h>

#define NODES 1430
#define GENE0 1421
#define NHEADS 9
#define GMAX 64              // max bucketed in-edges per gene
#define TPB 1024             // threads per persistent block
#define NB 240               // persistent blocks = KCH*RCH; 1/CU resident (128KB LDS)
#define KCH 80               // histogram chunks (multiple of 8 for XCD swizzle)
#define RCH 3                // histogram node-ranges
#define HBINS 262144         // bins per range (4-bit packed, 8/u32)
#define HWORDS (HBINS / 8)   // 32768 u32 = 128 KB LDS
#define QCAP2 4096           // scatter hit-queue (expected ~1375/block)

__device__ __forceinline__ float frelu(float v) { return v > 0.f ? v : 0.f; }

// Self-reinitializing grid barrier: cnt returns to 0 after each barrier,
// gen grows monotonically -> no host-side init, survives graph replays.
__device__ unsigned int g_cnt = 0;
__device__ unsigned int g_gen = 0;

__device__ __forceinline__ void grid_barrier() {
    __syncthreads();
    if (threadIdx.x == 0) {
        __threadfence();
        unsigned int old = __hip_atomic_load(&g_gen, __ATOMIC_ACQUIRE,
                                             __HIP_MEMORY_SCOPE_AGENT);
        unsigned int arr = __hip_atomic_fetch_add(&g_cnt, 1u, __ATOMIC_ACQ_REL,
                                                  __HIP_MEMORY_SCOPE_AGENT) + 1u;
        if (arr == gridDim.x) {
            __hip_atomic_store(&g_cnt, 0u, __ATOMIC_RELAXED,
                               __HIP_MEMORY_SCOPE_AGENT);
            __hip_atomic_fetch_add(&g_gen, 1u, __ATOMIC_RELEASE,
                                   __HIP_MEMORY_SCOPE_AGENT);
        } else {
            while (__hip_atomic_load(&g_gen, __ATOMIC_ACQUIRE,
                                     __HIP_MEMORY_SCOPE_AGENT) == old) {
                __builtin_amdgcn_s_sleep(1);
            }
        }
    }
    __syncthreads();
}

// Single persistent kernel: init -> hist(+gene detect) -> reduce -> scatter
// -> gene final. Replaces 5 dispatches (memset + 4 kernels) with 1, deleting
// ~4x per-dispatch launch overhead. 240 blocks x 1024 thr, 128 KB dyn LDS.
__global__ __launch_bounds__(TPB, 4)
void k_fused(const int* __restrict__ esrc, const int* __restrict__ edst,
             const float* __restrict__ x,
             unsigned int* __restrict__ copies,   // [KCH][RCH*HWORDS]
             int* __restrict__ gene_cnt, int* __restrict__ gene_src,
             unsigned int* __restrict__ flagw,
             float* __restrict__ t, float2* __restrict__ dx,
             const float* __restrict__ W1, const float* __restrict__ b1,
             const float* __restrict__ W2, const float* __restrict__ b2,
             const float* __restrict__ fw1, const float* __restrict__ fb1,
             const float* __restrict__ fw2, const float* __restrict__ fb2,
             float* __restrict__ out,
             int n, int e, int G, int NG, int nw) {
    extern __shared__ unsigned int lds[];
    __shared__ int qn;
    const int tid = threadIdx.x;
    const int bid = blockIdx.x;
    const int gtid = bid * TPB + tid;
    const int nthr = gridDim.x * TPB;

    // ---- phase 0: gene_cnt=0; flagw = gene-node self bits (single writer,
    // computed analytically -> no zero+atomicOr race, no memset dispatch) ----
    for (int i = gtid; i < NG; i += nthr) gene_cnt[i] = 0;
    for (int w = gtid; w < nw; w += nthr) {
        unsigned int m = 0;
        int base = w << 5;
#pragma unroll
        for (int b = 0; b < 32; b++) {
            int node = base + b;
            if (node < n) {
                unsigned int graph = (unsigned int)node / NODES;
                unsigned int pos = (unsigned int)node - graph * NODES;
                if (pos >= GENE0) m |= 1u << b;
            }
        }
        flagw[w] = m;
    }
    grid_barrier();

    // ---- phase A: privatized LDS nibble histogram + fused gene detect ----
    {
        int xcd = bid & 7;                 // XCD swizzle (KCH % 8 == 0)
        int slot = bid >> 3;
        int cin = slot / RCH;
        int k = xcd * (KCH >> 3) + cin;
        int r = slot - cin * RCH;

        uint4* l4 = (uint4*)lds;
        for (int w = tid; w < HWORDS / 4; w += TPB) l4[w] = make_uint4(0, 0, 0, 0);
        __syncthreads();

        const unsigned int lo = (unsigned int)r * HBINS;
        const int e4 = e >> 2;
        const int Q = (e4 + KCH - 1) / KCH;
        const int beg = k * Q;
        const int end = min(beg + Q, e4);
        const int4* ed4 = (const int4*)edst;
        const int len = (end > beg) ? (end - beg) : 0;
        const int eighth = len >> 3;

        auto proc = [&](int4 d4, int j4) {
#pragma unroll
            for (int c = 0; c < 4; c++) {
                unsigned int d = (unsigned int)((&d4.x)[c]);
                unsigned int rel = d - lo;
                if (rel < HBINS) {
                    atomicAdd(&lds[rel >> 3], 1u << ((rel & 7u) * 4u));
                    unsigned int graph = d / NODES;
                    unsigned int pos = d - graph * NODES;
                    if (pos >= GENE0) {
                        int s = esrc[4 * j4 + c];     // rare (0.63%) random load
                        atomicOr(&flagw[(unsigned)s >> 5], 1u << (s & 31));
                        int g = (int)(graph * NHEADS + (pos - GENE0));
                        int p = atomicAdd(gene_cnt + g, 1);
                        if (p < GMAX) gene_src[(g << 6) + p] = s;
                    }
                }
            }
        };

        for (int i = tid; i < eighth; i += TPB) {
            int j0 = beg + i;
            int4 v0 = ed4[j0];
            int4 v1 = ed4[j0 + eighth];
            int4 v2 = ed4[j0 + 2 * eighth];
            int4 v3 = ed4[j0 + 3 * eighth];
            int4 v4 = ed4[j0 + 4 * eighth];
            int4 v5 = ed4[j0 + 5 * eighth];
            int4 v6 = ed4[j0 + 6 * eighth];
            int4 v7 = ed4[j0 + 7 * eighth];
            proc(v0, j0);
            proc(v1, j0 + eighth);
            proc(v2, j0 + 2 * eighth);
            proc(v3, j0 + 3 * eighth);
            proc(v4, j0 + 4 * eighth);
            proc(v5, j0 + 5 * eighth);
            proc(v6, j0 + 6 * eighth);
            proc(v7, j0 + 7 * eighth);
        }
        for (int i = (eighth << 3) + tid; i < len; i += TPB) {
            proc(ed4[beg + i], beg + i);
        }
        if (k == 0) {                                   // tail edges (e % 4)
            for (int j = (e4 << 2) + tid; j < e; j += TPB) {
                unsigned int d = (unsigned int)edst[j];
                unsigned int rel = d - lo;
                if (rel < HBINS) {
                    atomicAdd(&lds[rel >> 3], 1u << ((rel & 7u) * 4u));
                    unsigned int graph = d / NODES;
                    unsigned int pos = d - graph * NODES;
                    if (pos >= GENE0) {
                        int s = esrc[j];
                        atomicOr(&flagw[(unsigned)s >> 5], 1u << (s & 31));
                        int g = (int)(graph * NHEADS + (pos - GENE0));
                        int p = atomicAdd(gene_cnt + g, 1);
                        if (p < GMAX) gene_src[(g << 6) + p] = s;
                    }
                }
            }
        }
        __syncthreads();
        int wlimit = (n > (int)lo) ? ((n - (int)lo + 7) >> 3) : 0;
        if (wlimit > HWORDS) wlimit = HWORDS;
        int w4 = (wlimit + 3) >> 2;
        uint4* dst4 = (uint4*)(copies + ((size_t)k * RCH + r) * HWORDS);
        const uint4* s4 = (const uint4*)lds;
        for (int w = tid; w < w4; w += TPB) dst4[w] = s4[w];
    }
    grid_barrier();

    // ---- phase B: SWAR-sum the KCH nibble copies -> dx={dinv,dinv*x}, t=0 ----
    {
        const int Wtot = RCH * HWORDS;
        const unsigned int M = 0x0F0F0F0Fu;
        for (int w = gtid; w < Wtot; w += nthr) {
            int i0 = w << 3;
            if (i0 >= n) continue;
            unsigned int ev[8] = {0, 0, 0, 0, 0, 0, 0, 0};
            unsigned int od[8] = {0, 0, 0, 0, 0, 0, 0, 0};
            for (int k = 0; k + 8 <= KCH; k += 8) {
#pragma unroll
                for (int s = 0; s < 8; s++) {
                    unsigned int u = copies[(size_t)(k + s) * Wtot + w];
                    ev[s] += u & M; od[s] += (u >> 4) & M;
                }
            }
            unsigned int evn = ((ev[0] + ev[1]) + (ev[2] + ev[3])) + ((ev[4] + ev[5]) + (ev[6] + ev[7]));
            unsigned int odd = ((od[0] + od[1]) + (od[2] + od[3])) + ((od[4] + od[5]) + (od[6] + od[7]));
            float v[8];
#pragma unroll
            for (int b = 0; b < 4; b++) {
                v[2 * b]     = (float)((evn >> (8 * b)) & 0xFFu);
                v[2 * b + 1] = (float)((odd >> (8 * b)) & 0xFFu);
            }
#pragma unroll
            for (int b = 0; b < 8; b++) v[b] = rsqrtf(v[b] + 1.f);
            float4 z4 = {0.f, 0.f, 0.f, 0.f};
            if (i0 + 7 < n) {
                float4 xa = *(const float4*)(x + i0);
                float4 xb = *(const float4*)(x + i0 + 4);
                float4 p0 = {v[0], v[0] * xa.x, v[1], v[1] * xa.y};
                float4 p1 = {v[2], v[2] * xa.z, v[3], v[3] * xa.w};
                float4 p2 = {v[4], v[4] * xb.x, v[5], v[5] * xb.y};
                float4 p3 = {v[6], v[6] * xb.z, v[7], v[7] * xb.w};
                float4* dst = (float4*)(dx + i0);
                dst[0] = p0; dst[1] = p1; dst[2] = p2; dst[3] = p3;
                *(float4*)(t + i0) = z4;
                *(float4*)(t + i0 + 4) = z4;
            } else {
                for (int b = 0; b < 8; b++)
                    if (i0 + b < n) {
                        dx[i0 + b] = make_float2(v[b], v[b] * x[i0 + b]);
                        t[i0 + b] = 0.f;
                    }
            }
        }
    }
    grid_barrier();

    // ---- phase C: layer-1 scatter; flag bitmap in LDS; dst-only scan;
    //      hits enqueue edge index; two-phase drain ----
    {
        unsigned int* fl = lds;                       // nw words (91.5 KB)
        int2* q = (int2*)(lds + ((nw + 3) & ~3));     // 32 KB queue
        if (tid == 0) qn = 0;
        const uint4* gl4 = (const uint4*)flagw;
        uint4* fl4 = (uint4*)fl;
        int nw4 = nw >> 2;
        for (int w = tid; w < nw4; w += TPB) fl4[w] = gl4[w];
        for (int w = (nw4 << 2) + tid; w < nw; w += TPB) fl[w] = flagw[w];
        __syncthreads();

        const int e4 = e >> 2;
        const int Q = (e4 + gridDim.x - 1) / gridDim.x;
        const int beg = bid * Q;
        const int end = min(beg + Q, e4);
        const int len = (end > beg) ? (end - beg) : 0;
        const int4* ed4 = (const int4*)edst;

        auto test = [&](int4 dd, int j4) {
#pragma unroll
            for (int c = 0; c < 4; c++) {
                int d = (&dd.x)[c];
                if ((fl[(unsigned)d >> 5] >> (d & 31)) & 1u) {
                    int p = atomicAdd(&qn, 1);
                    if (p < QCAP2) q[p] = make_int2(4 * j4 + c, d);
                    else atomicAdd(t + d, dx[esrc[4 * j4 + c]].y);
                }
            }
        };

        const int quarter = len >> 2;
        for (int i = tid; i < quarter; i += TPB) {
            int j0 = beg + i;
            int4 d0 = ed4[j0];
            int4 d1 = ed4[j0 + quarter];
            int4 d2 = ed4[j0 + 2 * quarter];
            int4 d3 = ed4[j0 + 3 * quarter];
            test(d0, j0);
            test(d1, j0 + quarter);
            test(d2, j0 + 2 * quarter);
            test(d3, j0 + 3 * quarter);
        }
        for (int i = (quarter << 2) + tid; i < len; i += TPB) {
            test(ed4[beg + i], beg + i);
        }
        if (bid == 0) {                                // tail edges
            for (int j = (e4 << 2) + tid; j < e; j += TPB) {
                int d = edst[j];
                if ((fl[(unsigned)d >> 5] >> (d & 31)) & 1u)
                    atomicAdd(t + d, dx[esrc[j]].y);
            }
        }
        __syncthreads();
        int m = min(qn, QCAP2);
        for (int i = tid; i < m; i += TPB) q[i].x = esrc[q[i].x];
        __syncthreads();
        for (int i = tid; i < m; i += TPB) {
            int2 sd = q[i];
            atomicAdd(t + sd.y, dx[sd.x].y);
        }
    }
    grid_barrier();

    // ---- phase D: gene final; 3840 waves loop over NG=4608 genes ----
    {
        int wid = gtid >> 6;
        int lane = tid & 63;
        int nwaves = nthr >> 6;
        const int c = lane & 15;
        const int slot = lane >> 4;
        for (int g = wid; g < NG; g += nwaves) {
            int graph = g / NHEADS;
            int head = g - graph * NHEADS;
            int node = graph * NODES + GENE0 + head;
            int cnt = min(gene_cnt[g], GMAX);

            float w1r[16], b1r[16], w2c[16];
#pragma unroll
            for (int kk = 0; kk < 16; kk++) {
                w1r[kk] = W1[kk];
                b1r[kk] = b1[kk];
                w2c[kk] = W2[kk * 16 + c];
            }
            float2 dn2 = dx[node];
            float tn = t[node];

            float acc = 0.f;
            const int base = g << 6;
            for (int i = slot; i < cnt; i += 8) {
                int s0 = gene_src[base + i];
                int i1 = i + 4;
                int s1 = (i1 < cnt) ? gene_src[base + i1] : -1;
                float2 a2 = dx[s0];
                float ta = t[s0];
                float2 b2v = (s1 >= 0) ? dx[s1] : make_float2(0.f, 0.f);
                float tb = (s1 >= 0) ? t[s1] : 0.f;
                {
                    float us = a2.x * ta + a2.x * a2.y;
                    float m2 = 0.f;
#pragma unroll
                    for (int kk = 0; kk < 16; kk++)
                        m2 += frelu(us * w1r[kk] + b1r[kk]) * w2c[kk];
                    acc += a2.x * m2;
                }
                if (s1 >= 0) {
                    float us = b2v.x * tb + b2v.x * b2v.y;
                    float m2 = 0.f;
#pragma unroll
                    for (int kk = 0; kk < 16; kk++)
                        m2 += frelu(us * w1r[kk] + b1r[kk]) * w2c[kk];
                    acc += b2v.x * m2;
                }
            }
            acc += __shfl_xor(acc, 16, 64);
            acc += __shfl_xor(acc, 32, 64);

            float dn = dn2.x;
            float un = dn * tn + dn * dn2.y;
            float h2 = 0.f;
#pragma unroll
            for (int kk = 0; kk < 16; kk++)
                h2 += frelu(un * w1r[kk] + b1r[kk]) * w2c[kk];
            float h = frelu(dn * acc + dn * dn * h2 + b2[c]);

            float hv[16];
#pragma unroll
            for (int c2 = 0; c2 < 16; c2++) hv[c2] = __shfl(h, c2, 64);

            int kk = lane & 7;
            float z = fb1[head * 8 + kk];
#pragma unroll
            for (int c2 = 0; c2 < 16; c2++) z += hv[c2] * fw1[head * 128 + c2 * 8 + kk];
            float term = frelu(z) * fw2[head * 8 + kk];
            term += __shfl_xor(term, 1, 64);
            term += __shfl_xor(term, 2, 64);
            term += __shfl_xor(term, 4, 64);
            if (lane == 0) out[head * G + graph] = fb2[head] + term;
        }
    }
}

extern "C" void kernel_launch(void* const* d_in, const int* in_sizes, int n_in,
                              void* d_out, int out_size, void* d_ws, size_t ws_size,
                              hipStream_t stream) {
    const float* x   = (const float*)d_in[0];
    const int*   ei  = (const int*)d_in[1];
    const float* W1  = (const float*)d_in[3];
    const float* b1  = (const float*)d_in[4];
    const float* W2  = (const float*)d_in[5];
    const float* b2  = (const float*)d_in[6];
    const float* fw1 = (const float*)d_in[7];
    const float* fb1 = (const float*)d_in[8];
    const float* fw2 = (const float*)d_in[9];
    const float* fb2 = (const float*)d_in[10];

    int n = in_sizes[0];
    int e = in_sizes[1] / 2;
    int G = in_sizes[2] / NHEADS;
    int NG = G * NHEADS;
    const int* esrc = ei;
    const int* edst = ei + e;
    int nw = (n + 31) / 32;

    // One-time: 128 KB dynamic LDS (gfx950 has 160 KiB/CU; proven in r1-r3).
    static int ATTR = 0;
    if (!ATTR) {
        hipFuncSetAttribute(reinterpret_cast<const void*>(k_fused),
                            hipFuncAttributeMaxDynamicSharedMemorySize, 131072);
        ATTR = 1;
    }

    char* ws = (char*)d_ws;
    size_t off = 0;
    auto alloc = [&](size_t bytes) {
        char* p = ws + off;
        off += (bytes + 255) & ~(size_t)255;
        return p;
    };
    int*    gene_cnt = (int*)alloc((size_t)NG * 4);
    unsigned int* flagw = (unsigned int*)alloc((size_t)nw * 4);
    int*    gene_src = (int*)alloc((size_t)NG * GMAX * 4);
    float*  t        = (float*)alloc((size_t)n * 4);
    float2* dx       = (float2*)alloc((size_t)n * 8);
    unsigned int* copies = (unsigned int*)alloc((size_t)KCH * RCH * HWORDS * 4);
    (void)n_in; (void)out_size; (void)ws_size;

    k_fused<<<NB, TPB, 131072, stream>>>(esrc, edst, x, copies,
                                         gene_cnt, gene_src, flagw, t, dx,
                                         W1, b1, W2, b2, fw1, fb1, fw2, fb2,
                                         (float*)d_out, n, e, G, NG, nw);
}

// Round 7
// 190.975 us; speedup vs baseline: 1.9257x; 1.8630x over previous
//
#include <hip/hip_runtime.h>

#define NODES 1430
#define GENE0 1421
#define NHEADS 9
#define BHIST 1024           // 16 waves/block (hist)
#define GMAX 64              // max bucketed in-edges per gene (Poisson(8) tail ~0)

__device__ __forceinline__ float frelu(float v) { return v > 0.f ? v : 0.f; }

// Pass 1: privatized LDS nibble histogram + fused gene detect (R3-proven).
__global__ __launch_bounds__(BHIST, 4)
void k_hist(const int* __restrict__ esrc, const int* __restrict__ edst,
            unsigned int* __restrict__ copies,      // [K][R*hwords]
            int* __restrict__ gene_cnt, int* __restrict__ gene_src,
            unsigned int* __restrict__ flagw,
            int e, int K, int R, int n, int hbins, int hwords) {
    extern __shared__ unsigned int lds[];
    int id = blockIdx.x;
    int k, r;
    if ((K & 7) == 0) {
        int xcd = id & 7;
        int slot = id >> 3;
        int cin = slot / R;
        k = xcd * (K >> 3) + cin;
        r = slot - cin * R;
    } else {
        k = id / R;
        r = id - k * R;
    }
    const int tid = threadIdx.x;
    {
        uint4* l4 = (uint4*)lds;
        const int hw4 = hwords >> 2;
        for (int w = tid; w < hw4; w += BHIST) l4[w] = make_uint4(0, 0, 0, 0);
    }
    __syncthreads();

    const unsigned int lo = (unsigned int)r * (unsigned int)hbins;
    const unsigned int hb = (unsigned int)hbins;
    const int e4 = e >> 2;
    const int Q = (e4 + K - 1) / K;
    const int beg = k * Q;
    const int end = min(beg + Q, e4);
    const int4* ed4 = (const int4*)edst;
    const int len = (end > beg) ? (end - beg) : 0;
    const int eighth = len >> 3;

    auto proc = [&](int4 d4, int j4) {
#pragma unroll
        for (int c = 0; c < 4; c++) {
            unsigned int d = (unsigned int)((&d4.x)[c]);
            unsigned int rel = d - lo;
            if (rel < hb) {
                atomicAdd(&lds[rel >> 3], 1u << ((rel & 7u) * 4u));
                unsigned int graph = d / NODES;
                unsigned int pos = d - graph * NODES;
                if (pos >= GENE0) {
                    int s = esrc[4 * j4 + c];       // rare (0.63%) random load
                    atomicOr(&flagw[(unsigned)s >> 5], 1u << (s & 31));
                    int g = (int)(graph * NHEADS + (pos - GENE0));
                    int p = atomicAdd(gene_cnt + g, 1);
                    if (p < GMAX) gene_src[(g << 6) + p] = s;
                }
            }
        }
    };

    for (int i = tid; i < eighth; i += BHIST) {
        int j0 = beg + i;
        int4 v0 = ed4[j0];
        int4 v1 = ed4[j0 + eighth];
        int4 v2 = ed4[j0 + 2 * eighth];
        int4 v3 = ed4[j0 + 3 * eighth];
        int4 v4 = ed4[j0 + 4 * eighth];
        int4 v5 = ed4[j0 + 5 * eighth];
        int4 v6 = ed4[j0 + 6 * eighth];
        int4 v7 = ed4[j0 + 7 * eighth];
        proc(v0, j0);
        proc(v1, j0 + eighth);
        proc(v2, j0 + 2 * eighth);
        proc(v3, j0 + 3 * eighth);
        proc(v4, j0 + 4 * eighth);
        proc(v5, j0 + 5 * eighth);
        proc(v6, j0 + 6 * eighth);
        proc(v7, j0 + 7 * eighth);
    }
    for (int i = (eighth << 3) + tid; i < len; i += BHIST) {
        proc(ed4[beg + i], beg + i);
    }
    if (k == 0) {                                   // tail edges (e % 4)
        for (int j = (e4 << 2) + tid; j < e; j += BHIST) {
            unsigned int d = (unsigned int)edst[j];
            unsigned int rel = d - lo;
            if (rel < hb) {
                atomicAdd(&lds[rel >> 3], 1u << ((rel & 7u) * 4u));
                unsigned int graph = d / NODES;
                unsigned int pos = d - graph * NODES;
                if (pos >= GENE0) {
                    int s = esrc[j];
                    atomicOr(&flagw[(unsigned)s >> 5], 1u << (s & 31));
                    int g = (int)(graph * NHEADS + (pos - GENE0));
                    int p = atomicAdd(gene_cnt + g, 1);
                    if (p < GMAX) gene_src[(g << 6) + p] = s;
                }
            }
        }
    }
    __syncthreads();
    int wlimit = (n > (int)lo) ? ((n - (int)lo + 7) >> 3) : 0;
    if (wlimit > hwords) wlimit = hwords;
    int w4 = (wlimit + 3) >> 2;
    uint4* dst4 = (uint4*)(copies + ((size_t)k * R + r) * hwords);
    const uint4* l4 = (const uint4*)lds;
    for (int w = tid; w < w4; w += BHIST) dst4[w] = l4[w];
}

// Pass 2: SWAR-sum the K nibble copies -> dx={dinv,dinv*x}, t=0.
// (Gene-node flag setting REMOVED: gene t is now computed in k_gene_final
// from the gene_src list, so flagw holds only gene-edge sources.)
__global__ void k_reduce(const unsigned int* __restrict__ copies,
                         const float* __restrict__ x,
                         float2* __restrict__ dx, float* __restrict__ t,
                         int n, int K, int Wtot) {
    int w = blockIdx.x * blockDim.x + threadIdx.x;
    if (w >= Wtot) return;
    int i0 = w << 3;
    if (i0 >= n) return;
    const unsigned int M = 0x0F0F0F0Fu;
    unsigned int ev[8] = {0, 0, 0, 0, 0, 0, 0, 0};
    unsigned int od[8] = {0, 0, 0, 0, 0, 0, 0, 0};
    int k = 0;
    for (; k + 8 <= K; k += 8) {
#pragma unroll
        for (int s = 0; s < 8; s++) {
            unsigned int u = copies[(size_t)(k + s) * Wtot + w];
            ev[s] += u & M; od[s] += (u >> 4) & M;
        }
    }
    for (; k < K; k++) {
        unsigned int u = copies[(size_t)k * Wtot + w];
        ev[0] += u & M; od[0] += (u >> 4) & M;
    }
    unsigned int evn = ((ev[0] + ev[1]) + (ev[2] + ev[3])) + ((ev[4] + ev[5]) + (ev[6] + ev[7]));
    unsigned int odd = ((od[0] + od[1]) + (od[2] + od[3])) + ((od[4] + od[5]) + (od[6] + od[7]));
    float v[8];
#pragma unroll
    for (int b = 0; b < 4; b++) {
        v[2 * b]     = (float)((evn >> (8 * b)) & 0xFFu);
        v[2 * b + 1] = (float)((odd >> (8 * b)) & 0xFFu);
    }
#pragma unroll
    for (int b = 0; b < 8; b++) v[b] = rsqrtf(v[b] + 1.f);
    float4 z4 = {0.f, 0.f, 0.f, 0.f};
    if (i0 + 7 < n) {
        float4 xa = *(const float4*)(x + i0);
        float4 xb = *(const float4*)(x + i0 + 4);
        float4 p0 = {v[0], v[0] * xa.x, v[1], v[1] * xa.y};
        float4 p1 = {v[2], v[2] * xa.z, v[3], v[3] * xa.w};
        float4 p2 = {v[4], v[4] * xb.x, v[5], v[5] * xb.y};
        float4 p3 = {v[6], v[6] * xb.z, v[7], v[7] * xb.w};
        float4* dst = (float4*)(dx + i0);
        dst[0] = p0; dst[1] = p1; dst[2] = p2; dst[3] = p3;
        *(float4*)(t + i0) = z4;
        *(float4*)(t + i0 + 4) = z4;
    } else {
        for (int b = 0; b < 8; b++)
            if (i0 + b < n) {
                dx[i0 + b] = make_float2(v[b], v[b] * x[i0 + b]);
                t[i0 + b] = 0.f;
            }
    }
}

// Pass 3 (new, MLP-oriented): per thread, 8 coalesced int4 dst loads
// (32 edges) -> 32 independent branchless flag loads -> direct atomics for
// the ~5% hits. No LDS queue, no serialization between stream and test.
// 256 thr x 8 blocks/CU = 32 waves/CU; ~40 independent loads in flight/wave.
__global__ __launch_bounds__(256, 8)
void k_l1_scatter(const int* __restrict__ esrc, const int* __restrict__ edst,
                  const float2* __restrict__ dx,
                  const unsigned int* __restrict__ flagw,
                  float* __restrict__ t, int e) {
    const int4* ed4 = (const int4*)edst;
    const int e4 = e >> 2;
    const int tid = threadIdx.x;
    const int base = blockIdx.x * 2048 + tid;       // int4 index, 8 streams

    int4 dv[8];
#pragma unroll
    for (int k = 0; k < 8; k++) {
        int j = base + k * 256;
        dv[k] = (j < e4) ? ed4[j] : make_int4(-1, -1, -1, -1);
    }
    unsigned int hm[8];
#pragma unroll
    for (int k = 0; k < 8; k++) {
        unsigned int m = 0;
#pragma unroll
        for (int c = 0; c < 4; c++) {
            int d = (&dv[k].x)[c];
            unsigned int widx = (d >= 0) ? ((unsigned)d >> 5) : 0u;
            unsigned int fw = flagw[widx];          // branchless, independent
            if (d >= 0 && ((fw >> (d & 31)) & 1u)) m |= 1u << c;
        }
        hm[k] = m;
    }
#pragma unroll
    for (int k = 0; k < 8; k++) {
        if (hm[k]) {
            int j = base + k * 256;
#pragma unroll
            for (int c = 0; c < 4; c++) {
                if ((hm[k] >> c) & 1u) {
                    int s = esrc[4 * j + c];
                    atomicAdd(t + (&dv[k].x)[c], dx[s].y);
                }
            }
        }
    }
    // tail edges (e % 4)
    if (blockIdx.x == 0) {
        for (int j = (e4 << 2) + tid; j < e; j += 256) {
            int d = edst[j];
            if ((flagw[(unsigned)d >> 5] >> (d & 31)) & 1u)
                atomicAdd(t + d, dx[esrc[j]].y);
        }
    }
}

// Pass 4: one wave per gene. tn (= t of the gene node) is now computed
// IN-REGISTER from the gene_src list (tsum of dx[s].y) instead of via the
// scatter -- the list entries are already being loaded for acc.
__global__ void k_gene_final(const int* __restrict__ gene_cnt, const int* __restrict__ gene_src,
                             const float* __restrict__ t, const float2* __restrict__ dx,
                             const float* __restrict__ W1, const float* __restrict__ b1,
                             const float* __restrict__ W2, const float* __restrict__ b2,
                             const float* __restrict__ fw1, const float* __restrict__ fb1,
                             const float* __restrict__ fw2, const float* __restrict__ fb2,
                             float* __restrict__ out, int NG, int G) {
    int wid = (blockIdx.x * blockDim.x + threadIdx.x) >> 6;
    int lane = threadIdx.x & 63;
    if (wid >= NG) return;
    int g = wid;
    int graph = g / NHEADS;
    int head = g - graph * NHEADS;
    int node = graph * NODES + GENE0 + head;
    const int c = lane & 15;
    const int slot = lane >> 4;
    int cnt = min(gene_cnt[g], GMAX);

    float w1r[16], b1r[16], w2c[16];
#pragma unroll
    for (int kk = 0; kk < 16; kk++) {
        w1r[kk] = W1[kk];
        b1r[kk] = b1[kk];
        w2c[kk] = W2[kk * 16 + c];
    }
    float2 dn2 = dx[node];

    float acc = 0.f, tsum = 0.f;
    const int base = g << 6;
    for (int i = slot; i < cnt; i += 8) {
        int s0 = gene_src[base + i];
        int i1 = i + 4;
        int s1 = (i1 < cnt) ? gene_src[base + i1] : -1;
        float2 a2 = dx[s0];
        float ta = t[s0];
        float2 b2v = (s1 >= 0) ? dx[s1] : make_float2(0.f, 0.f);
        float tb = (s1 >= 0) ? t[s1] : 0.f;
        tsum += a2.y + b2v.y;
        {
            float us = a2.x * ta + a2.x * a2.y;
            float m = 0.f;
#pragma unroll
            for (int kk = 0; kk < 16; kk++)
                m += frelu(us * w1r[kk] + b1r[kk]) * w2c[kk];
            acc += a2.x * m;
        }
        if (s1 >= 0) {
            float us = b2v.x * tb + b2v.x * b2v.y;
            float m = 0.f;
#pragma unroll
            for (int kk = 0; kk < 16; kk++)
                m += frelu(us * w1r[kk] + b1r[kk]) * w2c[kk];
            acc += b2v.x * m;
        }
    }
    acc += __shfl_xor(acc, 16, 64);
    acc += __shfl_xor(acc, 32, 64);
    tsum += __shfl_xor(tsum, 16, 64);
    tsum += __shfl_xor(tsum, 32, 64);

    float dn = dn2.x;
    float un = dn * tsum + dn * dn2.y;
    float h2 = 0.f;
#pragma unroll
    for (int kk = 0; kk < 16; kk++)
        h2 += frelu(un * w1r[kk] + b1r[kk]) * w2c[kk];
    float h = frelu(dn * acc + dn * dn * h2 + b2[c]);

    float hv[16];
#pragma unroll
    for (int c2 = 0; c2 < 16; c2++) hv[c2] = __shfl(h, c2, 64);

    int kk = lane & 7;
    float z = fb1[head * 8 + kk];
#pragma unroll
    for (int c2 = 0; c2 < 16; c2++) z += hv[c2] * fw1[head * 128 + c2 * 8 + kk];
    float term = frelu(z) * fw2[head * 8 + kk];
    term += __shfl_xor(term, 1, 64);
    term += __shfl_xor(term, 2, 64);
    term += __shfl_xor(term, 4, 64);
    if (lane == 0) out[head * G + graph] = fb2[head] + term;
}

extern "C" void kernel_launch(void* const* d_in, const int* in_sizes, int n_in,
                              void* d_out, int out_size, void* d_ws, size_t ws_size,
                              hipStream_t stream) {
    const float* x   = (const float*)d_in[0];
    const int*   ei  = (const int*)d_in[1];
    const float* W1  = (const float*)d_in[3];
    const float* b1  = (const float*)d_in[4];
    const float* W2  = (const float*)d_in[5];
    const float* b2  = (const float*)d_in[6];
    const float* fw1 = (const float*)d_in[7];
    const float* fb1 = (const float*)d_in[8];
    const float* fw2 = (const float*)d_in[9];
    const float* fb2 = (const float*)d_in[10];

    int n = in_sizes[0];
    int e = in_sizes[1] / 2;
    int G = in_sizes[2] / NHEADS;
    int NG = G * NHEADS;
    const int* esrc = ei;
    const int* edst = ei + e;
    int nw = (n + 31) / 32;

    // One-time: 128 KB dynamic LDS for k_hist (proven working R1-R3).
    static int HB_RT = 0;
    if (HB_RT == 0) {
        hipError_t st = hipFuncSetAttribute(
            reinterpret_cast<const void*>(k_hist),
            hipFuncAttributeMaxDynamicSharedMemorySize, 131072);
        HB_RT = (st == hipSuccess) ? 262144 : 131072;
    }
    const int HB = HB_RT;
    const int HW = HB >> 3;

    char* ws = (char*)d_ws;
    size_t off = 0;
    auto alloc = [&](size_t bytes) {
        char* p = ws + off;
        off += (bytes + 255) & ~(size_t)255;
        return p;
    };
    int*   gene_cnt      = (int*)alloc((size_t)NG * 4);
    unsigned int* flagw  = (unsigned int*)alloc((size_t)nw * 4);
    size_t zero_bytes    = off;
    int*    gene_src     = (int*)alloc((size_t)NG * GMAX * 4);
    float*  t            = (float*)alloc((size_t)n * 4);      // zeroed by k_reduce
    float2* dx           = (float2*)alloc((size_t)n * 8);     // {dinv, dinv*x}
    size_t fixed         = off;

    int R = (n + HB - 1) / HB;
    size_t per_copy = (size_t)R * HW * 4;
    int K = 80;
    if (fixed + (size_t)K * per_copy > ws_size) {
        size_t avail = (ws_size > fixed) ? (ws_size - fixed) : 0;
        int kfit = (int)(avail / per_copy);
        if (kfit >= 8) kfit &= ~7;
        K = kfit < 1 ? 1 : (kfit < K ? kfit : K);
    }
    unsigned int* copies = (unsigned int*)alloc((size_t)K * per_copy);
    (void)n_in; (void)out_size;

    hipMemsetAsync(d_ws, 0, zero_bytes, stream);

    const int B = 256;
    size_t shmem = (size_t)HW * 4;
    k_hist<<<K * R, BHIST, shmem, stream>>>(esrc, edst, copies, gene_cnt, gene_src,
                                            flagw, e, K, R, n, HB, HW);
    int Wtot = R * HW;
    k_reduce<<<(Wtot + B - 1) / B, B, 0, stream>>>(copies, x, dx, t, n, K, Wtot);
    int e4 = e >> 2;
    int nblk = (e4 + 2047) / 2048;                  // 8192 edges per block
    k_l1_scatter<<<nblk, 256, 0, stream>>>(esrc, edst, dx, flagw, t, e);
    int waves_blocks = (NG * 64 + B - 1) / B;
    k_gene_final<<<waves_blocks, B, 0, stream>>>(gene_cnt, gene_src, t, dx,
                                                 W1, b1, W2, b2,
                                                 fw1, fb1, fw2, fb2,
                                                 (float*)d_out, NG, G);
}